// Round 6
// baseline (1291.891 us; speedup 1.0000x reference)
//
#include <hip/hip_runtime.h>
#include <hip/hip_bf16.h>
#include <math.h>

#define B_ 8
#define N_ 512
#define K_ 128
#define M_ 100
#define NPAIR (B_*N_)    // 4096
#define DRLEN 1600
#define F0 240
#define NPAD 256

#define NLUT 2048
#define LUT_STRIDE 128
#define SMAX 1.5f
#define EPB 8            // LUT entries per block

using bf16x8 = __attribute__((ext_vector_type(8))) __bf16;
using f32x4  = __attribute__((ext_vector_type(4))) float;

static __device__ __forceinline__ float tanh_f(float x){
  float xc = fminf(fmaxf(x, -15.f), 15.f);
  float e = __expf(2.f*xc);
  return __fdividef(e - 1.f, e + 1.f);
}

// ---------------------------------------------------------------------------
// Parallel LUT build: block = EPB entries x 256 threads, h0/h1 in LDS.
// ---------------------------------------------------------------------------
__global__ __launch_bounds__(256) void lut_build_par(
    const float* __restrict__ ew0, const float* __restrict__ eb0,
    const float* __restrict__ ew1, const float* __restrict__ eb1,
    const float* __restrict__ ew2, const float* __restrict__ eb2,
    float* __restrict__ T)
{
  __shared__ float sh0[EPB][26];
  __shared__ float sh1[EPB][52];
  const int e0 = blockIdx.x * EPB;
  const int t = threadIdx.x;

  if (t < EPB*25){
    int e = t / 25, c = t % 25;
    float S = (float)(e0 + e) * (SMAX / (float)(NLUT - 1));
    sh0[e][c] = tanh_f(fmaf(S, ew0[c], eb0[c]));
  }
  __syncthreads();

  for (int o = t; o < EPB*50; o += 256){
    int e = o / 50, c = o % 50;
    float a = eb1[c], b = 0.f;
    #pragma unroll
    for (int k = 0; k < 24; k += 2){
      a = fmaf(sh0[e][k],   ew1[k*50 + c],     a);
      b = fmaf(sh0[e][k+1], ew1[(k+1)*50 + c], b);
    }
    a = fmaf(sh0[e][24], ew1[24*50 + c], a);
    sh1[e][c] = tanh_f(a + b);
  }
  __syncthreads();

  for (int o = t; o < EPB*M_; o += 256){
    int e = o / M_, c = o % M_;
    float a = eb2[c], b = 0.f;
    #pragma unroll
    for (int k = 0; k < 50; k += 2){
      a = fmaf(sh1[e][k],   ew2[k*M_ + c],     a);
      b = fmaf(sh1[e][k+1], ew2[(k+1)*M_ + c], b);
    }
    T[(size_t)(e0 + e)*LUT_STRIDE + c] = tanh_f(a + b);
  }
}

// ---------------------------------------------------------------------------
// Tiled transpose for W0: src [1600][240] f32 -> dst [256][1600] bf16 (n pad).
// 64x64 tiles, coalesced read AND write. Grid (25, 4).
// ---------------------------------------------------------------------------
__global__ __launch_bounds__(256) void prep_w0t(
    const float* __restrict__ src, __hip_bfloat16* __restrict__ dst)
{
  __shared__ float tile[64][65];
  const int k0 = blockIdx.x * 64;   // k tile (rows of src)
  const int n0 = blockIdx.y * 64;   // n tile (cols of src)
  const int tc = threadIdx.x & 63, tr = threadIdx.x >> 6;

  #pragma unroll
  for (int i = 0; i < 16; i += 1){
    int r = i*4 + tr;               // k offset
    int n = n0 + tc;
    tile[r][tc] = (n < F0) ? src[(size_t)(k0 + r)*F0 + n] : 0.f;
  }
  __syncthreads();
  #pragma unroll
  for (int i = 0; i < 16; i += 1){
    int r = i*4 + tr;               // n offset
    dst[(size_t)(n0 + r)*DRLEN + k0 + tc] = __float2bfloat16(tile[tc][r]);
  }
}

// ---------------------------------------------------------------------------
// Small prep: W1T/W2T transpose+bf16 (zero-padded [256][256]) + biases.
// ---------------------------------------------------------------------------
__global__ __launch_bounds__(256) void prep_small(
    const float* __restrict__ fw1, const float* __restrict__ fw2,
    const float* __restrict__ fb0, const float* __restrict__ fb1,
    const float* __restrict__ fb2,
    __hip_bfloat16* __restrict__ W1T, __hip_bfloat16* __restrict__ W2T,
    float* __restrict__ b0p, float* __restrict__ b1p, float* __restrict__ b2p)
{
  int idx = blockIdx.x*256 + threadIdx.x;
  if (idx < NPAD*NPAD){
    int n = idx / NPAD, k = idx % NPAD;
    W1T[idx] = __float2bfloat16((n < F0 && k < F0) ? fw1[(size_t)k*F0 + n] : 0.f);
  } else if (idx < 2*NPAD*NPAD){
    int j = idx - NPAD*NPAD;
    int n = j / NPAD, k = j % NPAD;
    W2T[j] = __float2bfloat16((n < F0 && k < F0) ? fw2[(size_t)k*F0 + n] : 0.f);
  } else if (idx < 2*NPAD*NPAD + 3*NPAD){
    int j = idx - 2*NPAD*NPAD;
    int which = j / NPAD, c = j % NPAD;
    const float* s = (which == 0) ? fb0 : (which == 1) ? fb1 : fb2;
    float* d = (which == 0) ? b0p : (which == 1) ? b1p : b2p;
    d[c] = (c < F0) ? s[c] : 0.f;
  }
}

// ---------------------------------------------------------------------------
// Embed: per (b,n) pair; LUT lerp; DR out in bf16 [pair][1600].
// ---------------------------------------------------------------------------
__global__ __launch_bounds__(128) void embed_kernel(
    const float* __restrict__ img, const float* __restrict__ T,
    __hip_bfloat16* __restrict__ DR)
{
  __shared__ float4 sRi[K_];
  __shared__ float2 sJW[K_];
  __shared__ float  sB[4][M_];

  const int pair = blockIdx.x;
  const int t = threadIdx.x;

  {
    float4 v = *(const float4*)(img + ((size_t)pair*K_ + t)*4);
    float x = v.x, y = v.y, z = v.z, fl = v.w;
    float R = fmaf(x, x, fmaf(y, y, z*z));
    bool mask = fl > 0.f;
    bool lt10 = R < 10.f;
    float safe = (R == 0.f) ? 1.f : R;
    float Sc = 0.5f*cosf(0.20943951023931953f*(R - 10.f)) + 0.5f;
    float S;
    if (mask && lt10)            S = 1.f/safe;
    else if (!lt10 && R < 25.f)  S = Sc;
    else                         S = 0.f;
    float coef = mask ? S/safe : 0.f;
    sRi[t] = make_float4(S, coef*x, coef*y, coef*z);

    float fidx = fminf(S, SMAX) * ((float)(NLUT - 1) / SMAX);
    float fi = floorf(fidx);
    int i = (int)fi;
    float w = fidx - fi;
    if (i > NLUT - 2){ i = NLUT - 2; w = 1.f; }
    sJW[t] = make_float2((float)i, w);
  }
  __syncthreads();

  if (t < M_){
    const int m = t;
    float a0 = 0.f, a1 = 0.f, a2 = 0.f, a3 = 0.f;
    #pragma unroll 4
    for (int j = 0; j < K_; j++){
      float2 jw = sJW[j];
      float4 ri = sRi[j];
      const float* r0 = T + (size_t)((int)jw.x) * LUT_STRIDE + m;
      float t0 = r0[0];
      float t1 = r0[LUT_STRIDE];
      float g = fmaf(jw.y, t1 - t0, t0);
      a0 = fmaf(ri.x, g, a0);
      a1 = fmaf(ri.y, g, a1);
      a2 = fmaf(ri.z, g, a2);
      a3 = fmaf(ri.w, g, a3);
    }
    sB[0][m] = a0; sB[1][m] = a1; sB[2][m] = a2; sB[3][m] = a3;
  }
  __syncthreads();

  __hip_bfloat16* drp = DR + (size_t)pair*DRLEN;
  for (int o = t; o < DRLEN; o += 128){
    int m = o / M_, h = o % M_;
    float d = sB[0][m]*sB[0][h] + sB[1][m]*sB[1][h]
            + sB[2][m]*sB[2][h] + sB[3][m]*sB[3][h];
    drp[o] = __float2bfloat16(d);
  }
}

// ---------------------------------------------------------------------------
// LDS double-buffered MFMA GEMM: Y[M][256] = tanh(A @ Bt^T + bias).
// A [M][K] bf16 row-major; Bt [256][K] bf16 (W^T, zero-padded).
// BM=64 BN=128 BK=64, 256 thr, 4 waves 2x2, wave tile 32x64.
// Depth-2 register prefetch feeds LDS double buffer (one sync per K-tile).
// LDS row stride 72 bf16 (144 B): all b128 ops at the 8-cyc bank floor.
// ---------------------------------------------------------------------------
__global__ __launch_bounds__(256) void gemm_lds(
    const __hip_bfloat16* __restrict__ A_, const __hip_bfloat16* __restrict__ Bt_,
    const float* __restrict__ bias, __hip_bfloat16* __restrict__ Y, int K)
{
  __shared__ __align__(16) __bf16 As[2][64][72];
  __shared__ __align__(16) __bf16 Bs[2][128][72];

  const __bf16* A  = (const __bf16*)A_;
  const __bf16* Bt = (const __bf16*)Bt_;
  const int tid = threadIdx.x;
  const int lane = tid & 63, wave = tid >> 6;
  const int wm = wave & 1, wn = wave >> 1;
  const int l15 = lane & 15, q = lane >> 4;
  const int row0 = blockIdx.x * 64;
  const int col0 = blockIdx.y * 128;

  // staging maps: A tile 64x64 = 512 16B-chunks (2/thread); B 128x64 = 1024 (4/thread)
  int arow[2], ac8[2]; size_t aoff[2];
  #pragma unroll
  for (int i = 0; i < 2; i++){
    int cid = tid + i*256; arow[i] = cid >> 3; ac8[i] = cid & 7;
    aoff[i] = (size_t)(row0 + arow[i])*K + ac8[i]*8;
  }
  int brow[4], bc8[4]; size_t boff[4];
  #pragma unroll
  for (int i = 0; i < 4; i++){
    int cid = tid + i*256; brow[i] = cid >> 3; bc8[i] = cid & 7;
    boff[i] = (size_t)(col0 + brow[i])*K + bc8[i]*8;
  }

  bf16x8 Ar[2][2], Br[2][4];
  const int niter = K >> 6;

  // prologue: tile0 -> LDS buf0; tile1 -> reg set1 (in flight)
  #pragma unroll
  for (int i = 0; i < 2; i++) Ar[0][i] = *(const bf16x8*)(A + aoff[i]);
  #pragma unroll
  for (int i = 0; i < 4; i++) Br[0][i] = *(const bf16x8*)(Bt + boff[i]);
  #pragma unroll
  for (int i = 0; i < 2; i++) *(bf16x8*)&As[0][arow[i]][ac8[i]*8] = Ar[0][i];
  #pragma unroll
  for (int i = 0; i < 4; i++) *(bf16x8*)&Bs[0][brow[i]][bc8[i]*8] = Br[0][i];
  #pragma unroll
  for (int i = 0; i < 2; i++) Ar[1][i] = *(const bf16x8*)(A + aoff[i] + 64);
  #pragma unroll
  for (int i = 0; i < 4; i++) Br[1][i] = *(const bf16x8*)(Bt + boff[i] + 64);
  __syncthreads();

  f32x4 acc[2][4] = {};

  for (int it = 0; it < niter; it++){
    const int buf = it & 1;
    #pragma unroll
    for (int ks = 0; ks < 2; ks++){
      bf16x8 a0 = *(const bf16x8*)&As[buf][wm*32 +      l15][ks*32 + q*8];
      bf16x8 a1 = *(const bf16x8*)&As[buf][wm*32 + 16 + l15][ks*32 + q*8];
      bf16x8 b0 = *(const bf16x8*)&Bs[buf][wn*64 +      l15][ks*32 + q*8];
      bf16x8 b1 = *(const bf16x8*)&Bs[buf][wn*64 + 16 + l15][ks*32 + q*8];
      bf16x8 b2 = *(const bf16x8*)&Bs[buf][wn*64 + 32 + l15][ks*32 + q*8];
      bf16x8 b3 = *(const bf16x8*)&Bs[buf][wn*64 + 48 + l15][ks*32 + q*8];
      acc[0][0] = __builtin_amdgcn_mfma_f32_16x16x32_bf16(a0, b0, acc[0][0], 0,0,0);
      acc[1][0] = __builtin_amdgcn_mfma_f32_16x16x32_bf16(a1, b0, acc[1][0], 0,0,0);
      acc[0][1] = __builtin_amdgcn_mfma_f32_16x16x32_bf16(a0, b1, acc[0][1], 0,0,0);
      acc[1][1] = __builtin_amdgcn_mfma_f32_16x16x32_bf16(a1, b1, acc[1][1], 0,0,0);
      acc[0][2] = __builtin_amdgcn_mfma_f32_16x16x32_bf16(a0, b2, acc[0][2], 0,0,0);
      acc[1][2] = __builtin_amdgcn_mfma_f32_16x16x32_bf16(a1, b2, acc[1][2], 0,0,0);
      acc[0][3] = __builtin_amdgcn_mfma_f32_16x16x32_bf16(a0, b3, acc[0][3], 0,0,0);
      acc[1][3] = __builtin_amdgcn_mfma_f32_16x16x32_bf16(a1, b3, acc[1][3], 0,0,0);
    }
    if (it + 1 < niter){
      const int nb = buf ^ 1;
      const int set = (it + 1) & 1;
      #pragma unroll
      for (int i = 0; i < 2; i++) *(bf16x8*)&As[nb][arow[i]][ac8[i]*8] = Ar[set][i];
      #pragma unroll
      for (int i = 0; i < 4; i++) *(bf16x8*)&Bs[nb][brow[i]][bc8[i]*8] = Br[set][i];
      if (it + 2 < niter){
        const int s2 = it & 1;
        const size_t k2 = (size_t)(it + 2) * 64;
        #pragma unroll
        for (int i = 0; i < 2; i++) Ar[s2][i] = *(const bf16x8*)(A + aoff[i] + k2);
        #pragma unroll
        for (int i = 0; i < 4; i++) Br[s2][i] = *(const bf16x8*)(Bt + boff[i] + k2);
      }
      __syncthreads();
    }
  }

  #pragma unroll
  for (int i = 0; i < 2; i++){
    #pragma unroll
    for (int j = 0; j < 4; j++){
      int c = col0 + wn*64 + j*16 + l15;
      float bs = bias[c];
      #pragma unroll
      for (int r = 0; r < 4; r++){
        int rr = row0 + wm*32 + i*16 + q*4 + r;
        float v = tanh_f(acc[i][j][r] + bs);
        Y[(size_t)rr*NPAD + c] = __float2bfloat16(v);
      }
    }
  }
}

// ---------------------------------------------------------------------------
// GEMV: Ei[m] = H[m,:240] . w3 + b3 ; one wave per row. H is bf16 [m][256].
// ---------------------------------------------------------------------------
__global__ __launch_bounds__(256) void gemv_out(
    const __hip_bfloat16* __restrict__ H, const float* __restrict__ w3,
    const float* __restrict__ b3, float* __restrict__ Ei,
    float* __restrict__ outEi)
{
  int row  = (blockIdx.x * 256 + threadIdx.x) >> 6;
  int lane = threadIdx.x & 63;
  const __hip_bfloat16* hp = H + (size_t)row * NPAD;
  float a = 0.f;
  for (int k = lane; k < F0; k += 64) a = fmaf(__bfloat162float(hp[k]), w3[k], a);
  #pragma unroll
  for (int off = 32; off; off >>= 1) a += __shfl_down(a, off, 64);
  if (lane == 0){
    float e = a + b3[0];
    Ei[row] = e;
    outEi[row] = e;
  }
}

__global__ __launch_bounds__(256) void etot_k(
    const float* __restrict__ Ei, float* __restrict__ outE)
{
  int b = blockIdx.x;
  int t = threadIdx.x;
  float s = Ei[b*N_ + t] + Ei[b*N_ + 256 + t];
  #pragma unroll
  for (int off = 32; off; off >>= 1) s += __shfl_down(s, off, 64);
  __shared__ float ws[4];
  if ((t & 63) == 0) ws[t >> 6] = s;
  __syncthreads();
  if (t == 0) outE[b] = ws[0] + ws[1] + ws[2] + ws[3];
}

extern "C" void kernel_launch(void* const* d_in, const int* in_sizes, int n_in,
                              void* d_out, int out_size, void* d_ws, size_t ws_size,
                              hipStream_t stream)
{
  const float* img = (const float*)d_in[0];
  const float* ew0 = (const float*)d_in[1];
  const float* eb0 = (const float*)d_in[2];
  const float* ew1 = (const float*)d_in[3];
  const float* eb1 = (const float*)d_in[4];
  const float* ew2 = (const float*)d_in[5];
  const float* eb2 = (const float*)d_in[6];
  const float* fw0 = (const float*)d_in[7];
  const float* fb0 = (const float*)d_in[8];
  const float* fw1 = (const float*)d_in[9];
  const float* fb1 = (const float*)d_in[10];
  const float* fw2 = (const float*)d_in[11];
  const float* fb2 = (const float*)d_in[12];
  const float* fw3 = (const float*)d_in[13];
  const float* fb3 = (const float*)d_in[14];

  char* w = (char*)d_ws;
  __hip_bfloat16* DRb = (__hip_bfloat16*)(w);                 // 13107200 B
  __hip_bfloat16* H1b = (__hip_bfloat16*)(w + 13107200);      // 2097152 B
  __hip_bfloat16* H2b = (__hip_bfloat16*)(w + 15204352);
  __hip_bfloat16* H3b = (__hip_bfloat16*)(w + 17301504);
  __hip_bfloat16* W0T = (__hip_bfloat16*)(w + 19398656);      // 819200 B
  __hip_bfloat16* W1T = (__hip_bfloat16*)(w + 20217856);      // 131072 B
  __hip_bfloat16* W2T = (__hip_bfloat16*)(w + 20348928);      // 131072 B
  float* b0p = (float*)(w + 20480000);                        // 1024 B
  float* b1p = (float*)(w + 20481024);
  float* b2p = (float*)(w + 20482048);
  float* LUT = (float*)(w + 20483072);                        // 1048576 B
  float* Ei  = (float*)(w + 21531648);                        // 16384 B

  float* out = (float*)d_out;                                 // [0..7]=Etot, [8..]=Ei

  prep_w0t<<<dim3(DRLEN/64, NPAD/64), 256, 0, stream>>>(fw0, W0T);
  const int small_elems = 2*NPAD*NPAD + 3*NPAD;
  prep_small<<<(small_elems + 255)/256, 256, 0, stream>>>(
      fw1, fw2, fb0, fb1, fb2, W1T, W2T, b0p, b1p, b2p);

  lut_build_par<<<NLUT/EPB, 256, 0, stream>>>(ew0, eb0, ew1, eb1, ew2, eb2, LUT);
  embed_kernel<<<NPAIR, 128, 0, stream>>>(img, LUT, DRb);

  dim3 gg(NPAIR/64, NPAD/128);
  gemm_lds<<<gg, 256, 0, stream>>>(DRb, W0T, b0p, H1b, DRLEN);
  gemm_lds<<<gg, 256, 0, stream>>>(H1b, W1T, b1p, H2b, NPAD);
  gemm_lds<<<gg, 256, 0, stream>>>(H2b, W2T, b2p, H3b, NPAD);

  gemv_out<<<NPAIR/4, 256, 0, stream>>>(H3b, fw3, fb3, Ei, out + 8);
  etot_k<<<B_, 256, 0, stream>>>(Ei, out);
}

// Round 7
// 149.920 us; speedup vs baseline: 8.6172x; 8.6172x over previous
//
#include <hip/hip_runtime.h>
#include <hip/hip_bf16.h>
#include <math.h>

#define B_ 8
#define N_ 512
#define K_ 128
#define M_ 100
#define NPAIR (B_*N_)    // 4096
#define DRLEN 1600
#define F0 240
#define NPAD 256

#define NLUT 2048
#define LUT_STRIDE 128
#define SMAX 1.5f
#define EPB 8            // LUT entries per block

using bf16x8 = __attribute__((ext_vector_type(8))) __bf16;
using f32x4  = __attribute__((ext_vector_type(4))) float;

static __device__ __forceinline__ float tanh_f(float x){
  float xc = fminf(fmaxf(x, -15.f), 15.f);
  float e = __expf(2.f*xc);
  return __fdividef(e - 1.f, e + 1.f);
}

// ---------------------------------------------------------------------------
// Parallel LUT build: block = EPB entries x 256 threads, h0/h1 in LDS.
// ---------------------------------------------------------------------------
__global__ __launch_bounds__(256) void lut_build_par(
    const float* __restrict__ ew0, const float* __restrict__ eb0,
    const float* __restrict__ ew1, const float* __restrict__ eb1,
    const float* __restrict__ ew2, const float* __restrict__ eb2,
    float* __restrict__ T)
{
  __shared__ float sh0[EPB][26];
  __shared__ float sh1[EPB][52];
  const int e0 = blockIdx.x * EPB;
  const int t = threadIdx.x;

  if (t < EPB*25){
    int e = t / 25, c = t % 25;
    float S = (float)(e0 + e) * (SMAX / (float)(NLUT - 1));
    sh0[e][c] = tanh_f(fmaf(S, ew0[c], eb0[c]));
  }
  __syncthreads();

  for (int o = t; o < EPB*50; o += 256){
    int e = o / 50, c = o % 50;
    float a = eb1[c], b = 0.f;
    #pragma unroll
    for (int k = 0; k < 24; k += 2){
      a = fmaf(sh0[e][k],   ew1[k*50 + c],     a);
      b = fmaf(sh0[e][k+1], ew1[(k+1)*50 + c], b);
    }
    a = fmaf(sh0[e][24], ew1[24*50 + c], a);
    sh1[e][c] = tanh_f(a + b);
  }
  __syncthreads();

  for (int o = t; o < EPB*M_; o += 256){
    int e = o / M_, c = o % M_;
    float a = eb2[c], b = 0.f;
    #pragma unroll
    for (int k = 0; k < 50; k += 2){
      a = fmaf(sh1[e][k],   ew2[k*M_ + c],     a);
      b = fmaf(sh1[e][k+1], ew2[(k+1)*M_ + c], b);
    }
    T[(size_t)(e0 + e)*LUT_STRIDE + c] = tanh_f(a + b);
  }
}

// ---------------------------------------------------------------------------
// Tiled transpose for W0: src [1600][240] f32 -> dst [256][1600] bf16 (n pad).
// ---------------------------------------------------------------------------
__global__ __launch_bounds__(256) void prep_w0t(
    const float* __restrict__ src, __hip_bfloat16* __restrict__ dst)
{
  __shared__ float tile[64][65];
  const int k0 = blockIdx.x * 64;
  const int n0 = blockIdx.y * 64;
  const int tc = threadIdx.x & 63, tr = threadIdx.x >> 6;

  #pragma unroll
  for (int i = 0; i < 16; i += 1){
    int r = i*4 + tr;
    int n = n0 + tc;
    tile[r][tc] = (n < F0) ? src[(size_t)(k0 + r)*F0 + n] : 0.f;
  }
  __syncthreads();
  #pragma unroll
  for (int i = 0; i < 16; i += 1){
    int r = i*4 + tr;
    dst[(size_t)(n0 + r)*DRLEN + k0 + tc] = __float2bfloat16(tile[tc][r]);
  }
}

// ---------------------------------------------------------------------------
// Small prep: W1T/W2T transpose+bf16 (zero-padded [256][256]) + biases.
// ---------------------------------------------------------------------------
__global__ __launch_bounds__(256) void prep_small(
    const float* __restrict__ fw1, const float* __restrict__ fw2,
    const float* __restrict__ fb0, const float* __restrict__ fb1,
    const float* __restrict__ fb2,
    __hip_bfloat16* __restrict__ W1T, __hip_bfloat16* __restrict__ W2T,
    float* __restrict__ b0p, float* __restrict__ b1p, float* __restrict__ b2p)
{
  int idx = blockIdx.x*256 + threadIdx.x;
  if (idx < NPAD*NPAD){
    int n = idx / NPAD, k = idx % NPAD;
    W1T[idx] = __float2bfloat16((n < F0 && k < F0) ? fw1[(size_t)k*F0 + n] : 0.f);
  } else if (idx < 2*NPAD*NPAD){
    int j = idx - NPAD*NPAD;
    int n = j / NPAD, k = j % NPAD;
    W2T[j] = __float2bfloat16((n < F0 && k < F0) ? fw2[(size_t)k*F0 + n] : 0.f);
  } else if (idx < 2*NPAD*NPAD + 3*NPAD){
    int j = idx - 2*NPAD*NPAD;
    int which = j / NPAD, c = j % NPAD;
    const float* s = (which == 0) ? fb0 : (which == 1) ? fb1 : fb2;
    float* d = (which == 0) ? b0p : (which == 1) ? b1p : b2p;
    d[c] = (c < F0) ? s[c] : 0.f;
  }
}

// ---------------------------------------------------------------------------
// Embed: per (b,n) pair; LUT lerp; DR out in bf16 [pair][1600].
// ---------------------------------------------------------------------------
__global__ __launch_bounds__(128) void embed_kernel(
    const float* __restrict__ img, const float* __restrict__ T,
    __hip_bfloat16* __restrict__ DR)
{
  __shared__ float4 sRi[K_];
  __shared__ float2 sJW[K_];
  __shared__ float  sB[4][M_];

  const int pair = blockIdx.x;
  const int t = threadIdx.x;

  {
    float4 v = *(const float4*)(img + ((size_t)pair*K_ + t)*4);
    float x = v.x, y = v.y, z = v.z, fl = v.w;
    float R = fmaf(x, x, fmaf(y, y, z*z));
    bool mask = fl > 0.f;
    bool lt10 = R < 10.f;
    float safe = (R == 0.f) ? 1.f : R;
    float Sc = 0.5f*cosf(0.20943951023931953f*(R - 10.f)) + 0.5f;
    float S;
    if (mask && lt10)            S = 1.f/safe;
    else if (!lt10 && R < 25.f)  S = Sc;
    else                         S = 0.f;
    float coef = mask ? S/safe : 0.f;
    sRi[t] = make_float4(S, coef*x, coef*y, coef*z);

    float fidx = fminf(S, SMAX) * ((float)(NLUT - 1) / SMAX);
    float fi = floorf(fidx);
    int i = (int)fi;
    float w = fidx - fi;
    if (i > NLUT - 2){ i = NLUT - 2; w = 1.f; }
    sJW[t] = make_float2((float)i, w);
  }
  __syncthreads();

  if (t < M_){
    const int m = t;
    float a0 = 0.f, a1 = 0.f, a2 = 0.f, a3 = 0.f;
    #pragma unroll 4
    for (int j = 0; j < K_; j++){
      float2 jw = sJW[j];
      float4 ri = sRi[j];
      const float* r0 = T + (size_t)((int)jw.x) * LUT_STRIDE + m;
      float t0 = r0[0];
      float t1 = r0[LUT_STRIDE];
      float g = fmaf(jw.y, t1 - t0, t0);
      a0 = fmaf(ri.x, g, a0);
      a1 = fmaf(ri.y, g, a1);
      a2 = fmaf(ri.z, g, a2);
      a3 = fmaf(ri.w, g, a3);
    }
    sB[0][m] = a0; sB[1][m] = a1; sB[2][m] = a2; sB[3][m] = a3;
  }
  __syncthreads();

  __hip_bfloat16* drp = DR + (size_t)pair*DRLEN;
  for (int o = t; o < DRLEN; o += 128){
    int m = o / M_, h = o % M_;
    float d = sB[0][m]*sB[0][h] + sB[1][m]*sB[1][h]
            + sB[2][m]*sB[2][h] + sB[3][m]*sB[3][h];
    drp[o] = __float2bfloat16(d);
  }
}

// ---------------------------------------------------------------------------
// LDS double-buffered MFMA GEMM, fully unrolled (template K/NITER so all
// register-array indices are compile-time -> no scratch demotion).
// Y[M][256] = tanh(A @ Bt^T + bias). A [M][K] bf16; Bt [256][K] bf16.
// BM=64 BN=64 BK=64, 256 thr = 4 waves (2x2), wave tile 32x32.
// LDS row stride 72 bf16: staging + frag reads at the b128 bank floor.
// Grid (M/64, 4) = 256 blocks, LDS 36 KB -> 4 blocks/CU.
// ---------------------------------------------------------------------------
template<int KK, int NITER>
__global__ __launch_bounds__(256) void gemm_lds(
    const __hip_bfloat16* __restrict__ A_, const __hip_bfloat16* __restrict__ Bt_,
    const float* __restrict__ bias, __hip_bfloat16* __restrict__ Y)
{
  __shared__ __align__(16) __bf16 As[2][64][72];
  __shared__ __align__(16) __bf16 Bs[2][64][72];

  const __bf16* A  = (const __bf16*)A_;
  const __bf16* Bt = (const __bf16*)Bt_;
  const int tid = threadIdx.x;
  const int lane = tid & 63, wave = tid >> 6;
  const int wm = wave & 1, wn = wave >> 1;
  const int l15 = lane & 15, q = lane >> 4;
  const int row0 = blockIdx.x * 64;
  const int col0 = blockIdx.y * 64;

  // staging: tile 64x64 bf16 = 512 16B-chunks, 2 per thread
  int arow[2], ac8[2]; size_t aoff[2], boff[2];
  #pragma unroll
  for (int i = 0; i < 2; i++){
    int cid = tid + i*256; arow[i] = cid >> 3; ac8[i] = cid & 7;
    aoff[i] = (size_t)(row0 + arow[i])*KK + ac8[i]*8;
    boff[i] = (size_t)(col0 + arow[i])*KK + ac8[i]*8;
  }

  bf16x8 Ar[2][2], Br[2][2];

  // prologue: tile0 -> LDS buf0; tile1 -> reg set1
  #pragma unroll
  for (int i = 0; i < 2; i++) Ar[0][i] = *(const bf16x8*)(A + aoff[i]);
  #pragma unroll
  for (int i = 0; i < 2; i++) Br[0][i] = *(const bf16x8*)(Bt + boff[i]);
  #pragma unroll
  for (int i = 0; i < 2; i++) *(bf16x8*)&As[0][arow[i]][ac8[i]*8] = Ar[0][i];
  #pragma unroll
  for (int i = 0; i < 2; i++) *(bf16x8*)&Bs[0][arow[i]][ac8[i]*8] = Br[0][i];
  #pragma unroll
  for (int i = 0; i < 2; i++) Ar[1][i] = *(const bf16x8*)(A + aoff[i] + 64);
  #pragma unroll
  for (int i = 0; i < 2; i++) Br[1][i] = *(const bf16x8*)(Bt + boff[i] + 64);
  __syncthreads();

  f32x4 acc[2][2] = {};

  #pragma unroll
  for (int it = 0; it < NITER; it++){
    const int buf = it & 1;
    #pragma unroll
    for (int ks = 0; ks < 2; ks++){
      bf16x8 a0 = *(const bf16x8*)&As[buf][wm*32 +      l15][ks*32 + q*8];
      bf16x8 a1 = *(const bf16x8*)&As[buf][wm*32 + 16 + l15][ks*32 + q*8];
      bf16x8 b0 = *(const bf16x8*)&Bs[buf][wn*32 +      l15][ks*32 + q*8];
      bf16x8 b1 = *(const bf16x8*)&Bs[buf][wn*32 + 16 + l15][ks*32 + q*8];
      acc[0][0] = __builtin_amdgcn_mfma_f32_16x16x32_bf16(a0, b0, acc[0][0], 0,0,0);
      acc[1][0] = __builtin_amdgcn_mfma_f32_16x16x32_bf16(a1, b0, acc[1][0], 0,0,0);
      acc[0][1] = __builtin_amdgcn_mfma_f32_16x16x32_bf16(a0, b1, acc[0][1], 0,0,0);
      acc[1][1] = __builtin_amdgcn_mfma_f32_16x16x32_bf16(a1, b1, acc[1][1], 0,0,0);
    }
    if (it + 1 < NITER){
      const int nb = buf ^ 1;
      const int set = (it + 1) & 1;
      #pragma unroll
      for (int i = 0; i < 2; i++) *(bf16x8*)&As[nb][arow[i]][ac8[i]*8] = Ar[set][i];
      #pragma unroll
      for (int i = 0; i < 2; i++) *(bf16x8*)&Bs[nb][arow[i]][ac8[i]*8] = Br[set][i];
      if (it + 2 < NITER){
        const int s2 = it & 1;
        const size_t k2 = (size_t)(it + 2) * 64;
        #pragma unroll
        for (int i = 0; i < 2; i++) Ar[s2][i] = *(const bf16x8*)(A + aoff[i] + k2);
        #pragma unroll
        for (int i = 0; i < 2; i++) Br[s2][i] = *(const bf16x8*)(Bt + boff[i] + k2);
      }
      __syncthreads();
    }
  }

  #pragma unroll
  for (int i = 0; i < 2; i++){
    #pragma unroll
    for (int j = 0; j < 2; j++){
      int c = col0 + wn*32 + j*16 + l15;
      float bs = bias[c];
      #pragma unroll
      for (int r = 0; r < 4; r++){
        int rr = row0 + wm*32 + i*16 + q*4 + r;
        float v = tanh_f(acc[i][j][r] + bs);
        Y[(size_t)rr*NPAD + c] = __float2bfloat16(v);
      }
    }
  }
}

// ---------------------------------------------------------------------------
// GEMV: Ei[m] = H[m,:240] . w3 + b3 ; one wave per row. H is bf16 [m][256].
// ---------------------------------------------------------------------------
__global__ __launch_bounds__(256) void gemv_out(
    const __hip_bfloat16* __restrict__ H, const float* __restrict__ w3,
    const float* __restrict__ b3, float* __restrict__ Ei,
    float* __restrict__ outEi)
{
  int row  = (blockIdx.x * 256 + threadIdx.x) >> 6;
  int lane = threadIdx.x & 63;
  const __hip_bfloat16* hp = H + (size_t)row * NPAD;
  float a = 0.f;
  for (int k = lane; k < F0; k += 64) a = fmaf(__bfloat162float(hp[k]), w3[k], a);
  #pragma unroll
  for (int off = 32; off; off >>= 1) a += __shfl_down(a, off, 64);
  if (lane == 0){
    float e = a + b3[0];
    Ei[row] = e;
    outEi[row] = e;
  }
}

__global__ __launch_bounds__(256) void etot_k(
    const float* __restrict__ Ei, float* __restrict__ outE)
{
  int b = blockIdx.x;
  int t = threadIdx.x;
  float s = Ei[b*N_ + t] + Ei[b*N_ + 256 + t];
  #pragma unroll
  for (int off = 32; off; off >>= 1) s += __shfl_down(s, off, 64);
  __shared__ float ws[4];
  if ((t & 63) == 0) ws[t >> 6] = s;
  __syncthreads();
  if (t == 0) outE[b] = ws[0] + ws[1] + ws[2] + ws[3];
}

extern "C" void kernel_launch(void* const* d_in, const int* in_sizes, int n_in,
                              void* d_out, int out_size, void* d_ws, size_t ws_size,
                              hipStream_t stream)
{
  const float* img = (const float*)d_in[0];
  const float* ew0 = (const float*)d_in[1];
  const float* eb0 = (const float*)d_in[2];
  const float* ew1 = (const float*)d_in[3];
  const float* eb1 = (const float*)d_in[4];
  const float* ew2 = (const float*)d_in[5];
  const float* eb2 = (const float*)d_in[6];
  const float* fw0 = (const float*)d_in[7];
  const float* fb0 = (const float*)d_in[8];
  const float* fw1 = (const float*)d_in[9];
  const float* fb1 = (const float*)d_in[10];
  const float* fw2 = (const float*)d_in[11];
  const float* fb2 = (const float*)d_in[12];
  const float* fw3 = (const float*)d_in[13];
  const float* fb3 = (const float*)d_in[14];

  char* w = (char*)d_ws;
  __hip_bfloat16* DRb = (__hip_bfloat16*)(w);                 // 13107200 B
  __hip_bfloat16* H1b = (__hip_bfloat16*)(w + 13107200);      // 2097152 B
  __hip_bfloat16* H2b = (__hip_bfloat16*)(w + 15204352);
  __hip_bfloat16* H3b = (__hip_bfloat16*)(w + 17301504);
  __hip_bfloat16* W0T = (__hip_bfloat16*)(w + 19398656);      // 819200 B
  __hip_bfloat16* W1T = (__hip_bfloat16*)(w + 20217856);      // 131072 B
  __hip_bfloat16* W2T = (__hip_bfloat16*)(w + 20348928);      // 131072 B
  float* b0p = (float*)(w + 20480000);                        // 1024 B
  float* b1p = (float*)(w + 20481024);
  float* b2p = (float*)(w + 20482048);
  float* LUT = (float*)(w + 20483072);                        // 1048576 B
  float* Ei  = (float*)(w + 21531648);                        // 16384 B

  float* out = (float*)d_out;                                 // [0..7]=Etot, [8..]=Ei

  prep_w0t<<<dim3(DRLEN/64, NPAD/64), 256, 0, stream>>>(fw0, W0T);
  const int small_elems = 2*NPAD*NPAD + 3*NPAD;
  prep_small<<<(small_elems + 255)/256, 256, 0, stream>>>(
      fw1, fw2, fb0, fb1, fb2, W1T, W2T, b0p, b1p, b2p);

  lut_build_par<<<NLUT/EPB, 256, 0, stream>>>(ew0, eb0, ew1, eb1, ew2, eb2, LUT);
  embed_kernel<<<NPAIR, 128, 0, stream>>>(img, LUT, DRb);

  dim3 gg(NPAIR/64, NPAD/64);
  gemm_lds<DRLEN, 25><<<gg, 256, 0, stream>>>(DRb, W0T, b0p, H1b);
  gemm_lds<NPAD,   4><<<gg, 256, 0, stream>>>(H1b, W1T, b1p, H2b);
  gemm_lds<NPAD,   4><<<gg, 256, 0, stream>>>(H2b, W2T, b2p, H3b);

  gemv_out<<<NPAIR/4, 256, 0, stream>>>(H3b, fw3, fb3, Ei, out + 8);
  etot_k<<<B_, 256, 0, stream>>>(Ei, out);
}